// Round 4
// baseline (808.288 us; speedup 1.0000x reference)
//
#include <hip/hip_runtime.h>
#include <hip/hip_fp16.h>
#include <math.h>

// Reference: bev (1024,1,120,120) fp32 -> out (1024,120) fp32.
// R11 green @712us: VALU-issue bound (VALUBusy 91%), conflicts 1.6e8 cyc,
// HBM 0.5%. Two images per block packed in half2 H[y][x]=(imgA,imgB).
// R12 FAILED (absmax 9.2e4 = unnormalized scale): invNorm was an ext_vector
// f32x2 in LDS; clang lowers element-assignment (invNorm.y = inv) as a full
// 8-byte load/insert/store RMW -> lanes 0,1 raced on the same word, leaving
// one half as LDS garbage. NOT a failure of the three VALU cuts.
// R13 = R12 with invNorm as float invN[2] (per-lane scalar stores, race-free).
// The three bit-identical VALU cuts, unchanged from R12:
//  (1) packed fp32 (v_pk_add/fma_f32 inline asm) for the y-lerp accumulate and
//      the whole Goertzel recurrence (6->3 VALU/iter);
//  (2) fract+trunc addressing (cx>=0 => trunc=floor; v_fract exact) replacing
//      floor/sub; clamp hi 121->121.5 only affects pad-zero reads;
//  (3) per-(angle,s) t-window: skip samples whose corners are all in the zero
//      pad (they added exact +0.0, incl. signed-zero analysis). Clamps kept =>
//      window is a trip-count cut, never a correctness dependency.
// Canary: absmax must be exactly 4.882812e-4 (bit-identical to R11).
#define NPIX  120
#define NS    120
#define NK    61             // independent bins 0..60; 61..119 mirrored
#define HSTR  123            // H cols: x = 0..122 (pads at 0, 121, 122)
#define HROWS 123            // H rows: y = 0..122 (pads at 0, 121, 122)
#define CHUNK 8              // angles in flight
#define NCHUNK 15            // 120 / 8
#define NT    960            // 8 angle-slots x 120, 15 waves

typedef float f32x2 __attribute__((ext_vector_type(2)));

__device__ __forceinline__ f32x2 pk_add2(f32x2 a, f32x2 b) {
    f32x2 d;
    asm("v_pk_add_f32 %0, %1, %2" : "=v"(d) : "v"(a), "v"(b));
    return d;
}
__device__ __forceinline__ f32x2 pk_fma2(f32x2 a, f32x2 b, f32x2 c) {
    f32x2 d;
    asm("v_pk_fma_f32 %0, %1, %2, %3" : "=v"(d) : "v"(a), "v"(b), "v"(c));
    return d;
}

#if __has_builtin(__builtin_amdgcn_fractf)
#define FRACTF(x) __builtin_amdgcn_fractf(x)
#else
#define FRACTF(x) ((x) - floorf(x))
#endif
#if __has_builtin(__builtin_amdgcn_rcpf)
#define RCPF(x) __builtin_amdgcn_rcpf(x)
#else
#define RCPF(x) (1.0f / (x))
#endif

// LDS: 123*123*4 (60,516) + 8*120*8 (7,680) + 61*8 + 8 = ~68.7 KB.
// 2 blocks/CU on gfx950's 160 KiB.

__global__ void ring_fused(const float* __restrict__ bev,
                           float* __restrict__ out,
                           int B) {
    __shared__ __half2 H[HROWS * HSTR];   // (imgA, imgB) packed padded image
    __shared__ f32x2 schunk[CHUNK * NS];  // 8 sinogram rows x 2 images
    __shared__ f32x2 outAcc[NK];
    __shared__ float invN[2];             // per-image 1/norm (scalar stores!)

    const int tid = threadIdx.x;          // 0..959
    const int b0  = blockIdx.x * 2;       // first image of the pair
    const int b1  = b0 + 1;
    const int al  = tid / NS;             // angle slot 0..7
    const int sk  = tid - al * NS;        // s (radon) / k (Goertzel, if <61)
    if (b0 >= B) return;

    // ---- stage: build H from both images (each word owned by 1 thread) -----
    const float* srcA = bev + (size_t)b0 * (NPIX * NPIX);
    const float* srcB = (b1 < B) ? bev + (size_t)b1 * (NPIX * NPIX) : srcA;
    for (int i = tid; i < HROWS * HSTR; i += NT) {
        int y = i / HSTR, x = i - y * HSTR;
        float va = 0.f, vb = 0.f;
        int gx = x - 1, gy = y - 1;
        if (gx >= 0 && gx < NPIX && gy >= 0 && gy < NPIX) {
            va = srcA[gy * NPIX + gx];
            vb = srcB[gy * NPIX + gx];
        }
        H[i] = __floats2half2_rn(va, vb);
    }
    __syncthreads();

    // ---- per-thread Goertzel constant (k = sk, used where sk < 61) ---------
    const float coef = 2.f * cosf((float)sk * 0.052359877559829887f);  // 2cos(pi k/60)
    const float sgn  = (sk & 1) ? -1.f : 1.f;
    const double STEP = 6.283185307179586 / 119.0;   // linspace(0,2pi,120) step
    float accKA = 0.f, accKB = 0.f;

    for (int ch = 0; ch < NCHUNK; ++ch) {
        // ---- radon: sinogram[a = ch*8+al][s = sk] for BOTH images ----------
        {
            int a = ch * CHUNK + al;
            float theta = (float)((double)a * STEP);
            float st = sinf(theta), ct = cosf(theta);
            float sf  = (float)sk - 59.5f;
            float Ax  = fmaf(sf, ct, 60.5f);   // padded px at tv=0
            float Ay  = fmaf(sf, st, 60.5f);   // padded py at tv=0
            float nst = -st;

            // t-window: superset of all t with nonzero contribution.
            // px(t) = Ax0 + t*nst; a sample is exactly zero unless px in (0,121)
            // (px<=0 -> wx=0 reads pad col 0; px>=121 -> both cols are pads).
            // Bounds use (-1.5, 123) margins to absorb rcp/rounding error.
            float Ax0 = fmaf(-59.5f, nst, Ax);
            float Ay0 = fmaf(-59.5f, ct,  Ay);
            float tlo = 0.f, thi = 119.f;
            if (fabsf(nst) > 1e-5f) {
                float r  = RCPF(nst);
                float e1 = (-1.5f - Ax0) * r;
                float e2 = (123.f - Ax0) * r;
                tlo = fmaxf(tlo, fminf(e1, e2));
                thi = fminf(thi, fmaxf(e1, e2));
            }
            if (fabsf(ct) > 1e-5f) {
                float r  = RCPF(ct);
                float e1 = (-1.5f - Ay0) * r;
                float e2 = (123.f - Ay0) * r;
                tlo = fmaxf(tlo, fminf(e1, e2));
                thi = fminf(thi, fmaxf(e1, e2));
            }
            int t0 = (int)fmaxf(tlo, 0.f);           // trunc=floor (arg>=0): start early = safe
            int t1 = min(119, (int)fminf(thi, 119.f) + 1);  // trunc+1 >= ceil: end late = safe

            f32x2 aT = {0.f, 0.f};
            float aDA = 0.f, aDB = 0.f;
            const f32x2 m1 = {-1.f, -1.f};
            float tv = (float)t0 - 59.5f;
            #pragma unroll 2
            for (int t = t0; t <= t1; ++t) {
                float px = fmaf(tv, nst, Ax);
                float py = fmaf(tv, ct,  Ay);
                float cx = fminf(fmaxf(px, 0.f), 121.5f);  // v_med3
                float cy = fminf(fmaxf(py, 0.f), 121.5f);
                int   ix = (int)cx;                        // trunc = floor (cx>=0)
                int   iy = (int)cy;
                float wx = FRACTF(cx);                     // == cx - floor(cx)
                float wy = FRACTF(cy);
                int   ai = __mul24(iy, HSTR) + ix;
                __half2 c00 = H[ai];                       // (A00,B00)
                __half2 c01 = H[ai + 1];                   // ds_read2_b32 pair 1
                __half2 c10 = H[ai + HSTR];                // (A10,B10)
                __half2 c11 = H[ai + HSTR + 1];            // ds_read2_b32 pair 2
                __half2 wx2 = __float2half2_rn(wx);
                __half2 th  = __hfma2(wx2, __hsub2(c01, c00), c00); // tops
                __half2 bh  = __hfma2(wx2, __hsub2(c11, c10), c10); // bottoms
                f32x2 tf = { __low2float(th), __high2float(th) };
                f32x2 bf = { __low2float(bh), __high2float(bh) };
                aT = pk_add2(aT, tf);
                f32x2 d2 = pk_fma2(m1, tf, bf);            // bf - tf (exact)
                aDA = fmaf(wy, d2.x, aDA);
                aDB = fmaf(wy, d2.y, aDB);
                tv += 1.f;
            }
            schunk[al * NS + sk] = (f32x2){aT.x + aDA, aT.y + aDB};
        }
        __syncthreads();

        // ---- Goertzel: |F[k = sk]| of row al, both images (sk < 61) --------
        if (sk < NK) {
            const f32x2* row = schunk + al * NS;
            f32x2 u1 = {0.f, 0.f}, u2 = {0.f, 0.f};
            const f32x2 sgn2  = {sgn, sgn};
            const f32x2 coef2 = {coef, coef};
            const f32x2 m1g   = {-1.f, -1.f};
            #pragma unroll 4
            for (int s = 0; s < 60; ++s) {
                f32x2 lo = row[s];             // broadcast ds_read_b64
                f32x2 hi = row[s + 60];
                f32x2 w  = pk_fma2(sgn2, hi, lo);            // lo + sgn*hi
                f32x2 v  = pk_fma2(coef2, u1, pk_fma2(m1g, u2, w)); // coef*u1 + (w-u2)
                u2 = u1; u1 = v;
            }
            float pa = fmaf(u1.x, u1.x, fmaf(u2.x, u2.x, -coef * u1.x * u2.x));
            float pb = fmaf(u1.y, u1.y, fmaf(u2.y, u2.y, -coef * u1.y * u2.y));
            pa = fmaxf(pa, 0.f);
            pb = fmaxf(pb, 0.f);
            accKA += sqrtf(fmaf(pa, (1.f / 120.f), 1e-15f));  // ortho + EPS_FFT
            accKB += sqrtf(fmaf(pb, (1.f / 120.f), 1e-15f));
        }
        __syncthreads();
    }

    // ---- reduce 8 angle-slot partials per bin (deterministic) --------------
    if (sk < NK) schunk[al * NS + sk] = (f32x2){accKA, accKB};
    __syncthreads();
    if (tid < NK) {
        float sa = 0.f, sb = 0.f;
        for (int a2 = 0; a2 < CHUNK; ++a2) {
            f32x2 v = schunk[a2 * NS + tid];
            sa += v.x;
            sb += v.y;
        }
        outAcc[tid] = (f32x2){sa, sb};
    }
    __syncthreads();

    // ---- L2 norm over the full mirrored 120-vector, one thread per image ---
    if (tid < 2) {
        float ssq = 0.f;
        for (int k = 0; k < NK; ++k) {
            f32x2 oa = outAcc[k];
            float v = tid ? oa.y : oa.x;
            float wgt = (k == 0 || k == 60) ? 1.f : 2.f;
            ssq = fmaf(wgt * v, v, ssq);
        }
        invN[tid] = 1.f / fmaxf(sqrtf(ssq), 1e-12f);  // per-lane scalar store
    }
    __syncthreads();

    // ---- write fp32 output (Hermitian mirror), both images -----------------
    if (tid < 2 * NPIX) {
        int img = tid / NPIX;
        int j   = tid - img * NPIX;
        int k   = (j <= 60) ? j : (NPIX - j);
        int bb  = b0 + img;
        if (bb < B) {
            f32x2 oa = outAcc[k];
            float v = (img ? oa.y : oa.x) * invN[img];
            out[(size_t)bb * NPIX + j] = v;
        }
    }
}

extern "C" void kernel_launch(void* const* d_in, const int* in_sizes, int n_in,
                              void* d_out, int out_size, void* d_ws, size_t ws_size,
                              hipStream_t stream) {
    const float* bev = (const float*)d_in[0];
    float* out = (float*)d_out;
    int B = in_sizes[0] / (NPIX * NPIX);   // 1024
    int grid = (B + 1) / 2;                // 2 images per block
    hipLaunchKernelGGL(ring_fused, dim3(grid), dim3(NT), 0, stream, bev, out, B);
}

// Round 5
// 690.863 us; speedup vs baseline: 1.1700x; 1.1700x over previous
//
#include <hip/hip_runtime.h>
#include <hip/hip_fp16.h>
#include <math.h>

// Reference: bev (1024,1,120,120) fp32 -> out (1024,120) fp32.
// R11 green @712us: VALU-issue bound (VALUBusy 91%), conflicts 1.6e8, HBM 0.5%.
// R13 green @808us but REGRESSED: post-mortem (a) v_pk_*_f32 is HALF-RATE on
// gfx950 (peak fp32 157.3 TF == scalar-fma rate) -> pk swap was issue-neutral
// plus reg-pair mov overhead; (b) t-window pays wave-MAX trips, not mean ->
// ~1-2% real cut < setup cost. Both reverted. Kept: fract/trunc addressing
// (bit-exact in R13, -2 ops).
// R14 = R11 chassis + fract/trunc addressing + FULL-fp16 bilinear:
//   y-lerp moves to packed fp16 (vh = hfma2(wy2, bh-th, th)), replacing the
//   fp32 tail (4 cvt + 2 add + 2 sub + 2 fma) with (1 pack + 2 hops + 2 cvt +
//   2 add). ~24 VALU/sample-pair vs ~29. Accumulation stays fp32 with
//   parity-split chains (ILP). Precision: +1 fp16 rounding per sample
//   (~3e-4), fp32 accum -> absmax ~1e-3 expected vs 1.976e-2 threshold.
#define NPIX  120
#define NS    120
#define NK    61             // independent bins 0..60; 61..119 mirrored
#define HSTR  123            // H cols: x = 0..122 (pads at 0, 121, 122)
#define HROWS 123            // H rows: y = 0..122 (pads at 0, 121, 122)
#define CHUNK 8              // angles in flight
#define NCHUNK 15            // 120 / 8
#define NT    960            // 8 angle-slots x 120, 15 waves

#if __has_builtin(__builtin_amdgcn_fractf)
#define FRACTF(x) __builtin_amdgcn_fractf(x)
#else
#define FRACTF(x) ((x) - floorf(x))
#endif

// LDS: 123*123*4 (60,516) + 8*120*8 (7,680) + 61*8 + 8 = ~68.7 KB.
// 2 blocks/CU on gfx950's 160 KiB.

__global__ void ring_fused(const float* __restrict__ bev,
                           float* __restrict__ out,
                           int B) {
    __shared__ __half2 H[HROWS * HSTR];   // (imgA, imgB) packed padded image
    __shared__ float2 schunk[CHUNK * NS]; // 8 sinogram rows x 2 images
    __shared__ float2 outAcc[NK];
    __shared__ float invN[2];             // per-image 1/norm (scalar stores)

    const int tid = threadIdx.x;          // 0..959
    const int b0  = blockIdx.x * 2;       // first image of the pair
    const int b1  = b0 + 1;
    const int al  = tid / NS;             // angle slot 0..7
    const int sk  = tid - al * NS;        // s (radon) / k (Goertzel, if <61)
    if (b0 >= B) return;

    // ---- stage: build H from both images (each word owned by 1 thread) -----
    const float* srcA = bev + (size_t)b0 * (NPIX * NPIX);
    const float* srcB = (b1 < B) ? bev + (size_t)b1 * (NPIX * NPIX) : srcA;
    for (int i = tid; i < HROWS * HSTR; i += NT) {
        int y = i / HSTR, x = i - y * HSTR;
        float va = 0.f, vb = 0.f;
        int gx = x - 1, gy = y - 1;
        if (gx >= 0 && gx < NPIX && gy >= 0 && gy < NPIX) {
            va = srcA[gy * NPIX + gx];
            vb = srcB[gy * NPIX + gx];
        }
        H[i] = __floats2half2_rn(va, vb);
    }
    __syncthreads();

    // ---- per-thread Goertzel constant (k = sk, used where sk < 61) ---------
    const float coef = 2.f * cosf((float)sk * 0.052359877559829887f);  // 2cos(pi k/60)
    const float sgn  = (sk & 1) ? -1.f : 1.f;
    const double STEP = 6.283185307179586 / 119.0;   // linspace(0,2pi,120) step
    float accKA = 0.f, accKB = 0.f;

    for (int ch = 0; ch < NCHUNK; ++ch) {
        // ---- radon: sinogram[a = ch*8+al][s = sk] for BOTH images ----------
        {
            int a = ch * CHUNK + al;
            float theta = (float)((double)a * STEP);
            float st = sinf(theta), ct = cosf(theta);
            float sf  = (float)sk - 59.5f;
            float Ax  = fmaf(sf, ct, 60.5f);   // padded px at tv=0
            float Ay  = fmaf(sf, st, 60.5f);   // padded py at tv=0
            float nst = -st;
            float aA0 = 0.f, aA1 = 0.f;        // img A: parity-split chains
            float aB0 = 0.f, aB1 = 0.f;        // img B
            float tv  = -59.5f;
            #pragma unroll 4
            for (int t = 0; t < NPIX; ++t) {
                float px = fmaf(tv, nst, Ax);
                float py = fmaf(tv, ct,  Ay);
                float cx = fminf(fmaxf(px, 0.f), 121.5f);  // v_med3
                float cy = fminf(fmaxf(py, 0.f), 121.5f);
                int   ix = (int)cx;                        // trunc = floor (cx>=0)
                int   iy = (int)cy;
                float wx = FRACTF(cx);                     // == cx - floor(cx)
                float wy = FRACTF(cy);
                int   ai = __mul24(iy, HSTR) + ix;
                __half2 c00 = H[ai];                       // (A00,B00)
                __half2 c01 = H[ai + 1];                   // ds_read2_b32 pair 1
                __half2 c10 = H[ai + HSTR];                // (A10,B10)
                __half2 c11 = H[ai + HSTR + 1];            // ds_read2_b32 pair 2
                __half2 wx2 = __float2half2_rn(wx);
                __half2 wy2 = __float2half2_rn(wy);
                __half2 th  = __hfma2(wx2, __hsub2(c01, c00), c00); // tops
                __half2 bh  = __hfma2(wx2, __hsub2(c11, c10), c10); // bottoms
                __half2 vh  = __hfma2(wy2, __hsub2(bh, th), th);    // bilinear
                if (t & 1) { aA1 += __low2float(vh); aB1 += __high2float(vh); }
                else       { aA0 += __low2float(vh); aB0 += __high2float(vh); }
                tv += 1.f;
            }
            schunk[al * NS + sk] = make_float2(aA0 + aA1, aB0 + aB1);
        }
        __syncthreads();

        // ---- Goertzel: |F[k = sk]| of row al, both images (sk < 61) --------
        if (sk < NK) {
            const float2* row = schunk + al * NS;
            float u1a = 0.f, u2a = 0.f, u1b = 0.f, u2b = 0.f;
            #pragma unroll 4
            for (int s = 0; s < 60; ++s) {
                float2 lo = row[s];            // broadcast ds_read_b64
                float2 hi = row[s + 60];
                float wa = fmaf(sgn, hi.x, lo.x);
                float wb = fmaf(sgn, hi.y, lo.y);
                float va = fmaf(coef, u1a, wa - u2a); u2a = u1a; u1a = va;
                float vb = fmaf(coef, u1b, wb - u2b); u2b = u1b; u1b = vb;
            }
            float pa = fmaf(u1a, u1a, fmaf(u2a, u2a, -coef * u1a * u2a));
            float pb = fmaf(u1b, u1b, fmaf(u2b, u2b, -coef * u1b * u2b));
            pa = fmaxf(pa, 0.f);
            pb = fmaxf(pb, 0.f);
            accKA += sqrtf(fmaf(pa, (1.f / 120.f), 1e-15f));  // ortho + EPS_FFT
            accKB += sqrtf(fmaf(pb, (1.f / 120.f), 1e-15f));
        }
        __syncthreads();
    }

    // ---- reduce 8 angle-slot partials per bin (deterministic) --------------
    if (sk < NK) schunk[al * NS + sk] = make_float2(accKA, accKB);
    __syncthreads();
    if (tid < NK) {
        float sa = 0.f, sb = 0.f;
        for (int a2 = 0; a2 < CHUNK; ++a2) {
            float2 v = schunk[a2 * NS + tid];
            sa += v.x;
            sb += v.y;
        }
        outAcc[tid] = make_float2(sa, sb);
    }
    __syncthreads();

    // ---- L2 norm over the full mirrored 120-vector, one thread per image ---
    if (tid < 2) {
        float ssq = 0.f;
        for (int k = 0; k < NK; ++k) {
            float2 oa = outAcc[k];
            float v = tid ? oa.y : oa.x;
            float wgt = (k == 0 || k == 60) ? 1.f : 2.f;
            ssq = fmaf(wgt * v, v, ssq);
        }
        invN[tid] = 1.f / fmaxf(sqrtf(ssq), 1e-12f);  // per-lane scalar store
    }
    __syncthreads();

    // ---- write fp32 output (Hermitian mirror), both images -----------------
    if (tid < 2 * NPIX) {
        int img = tid / NPIX;
        int j   = tid - img * NPIX;
        int k   = (j <= 60) ? j : (NPIX - j);
        int bb  = b0 + img;
        if (bb < B) {
            float2 oa = outAcc[k];
            float v = (img ? oa.y : oa.x) * invN[img];
            out[(size_t)bb * NPIX + j] = v;
        }
    }
}

extern "C" void kernel_launch(void* const* d_in, const int* in_sizes, int n_in,
                              void* d_out, int out_size, void* d_ws, size_t ws_size,
                              hipStream_t stream) {
    const float* bev = (const float*)d_in[0];
    float* out = (float*)d_out;
    int B = in_sizes[0] / (NPIX * NPIX);   // 1024
    int grid = (B + 1) / 2;                // 2 images per block
    hipLaunchKernelGGL(ring_fused, dim3(grid), dim3(NT), 0, stream, bev, out, B);
}

// Round 7
// 600.509 us; speedup vs baseline: 1.3460x; 1.1505x over previous
//
#include <hip/hip_runtime.h>
#include <hip/hip_fp16.h>
#include <math.h>

// Reference: bev (1024,1,120,120) fp32 -> out (1024,120) fp32.
// R14 green @691us: VALUBusy 87%, conflicts 1.62e8, HBM 0.5%. Calibration vs
// counters: ~45 issued VALU/sample-pair (~20 unmodeled overhead ops/sample,
// fixed per SAMPLE not per image) -> amortize over MORE images.
// R15 (re-run; previous submission died to a container-acquire infra failure,
// same signature as Round 2 which re-ran fine): FOUR images per block.
// H[y][x]=(A,B,C,D) as 4xfp16 in uint2 (8B texel).
//  - per-sample front end (px/py/med3/cvt/fract/mul24/packs + overhead) now
//    shared by 4 images; per-pair adds only 3 h-ops + 2 cvt + 2 add.
//  - all 4 bilinear corners x 4 images = 2x ds_read2_b64 (offsets 0/1 and
//    123/124): per-image DS instruction count HALVES, bytes unchanged.
//  - LDS: H 121,032 + schunk dbl-buf 30,720 + outAcc 976 + invN 16 = 152,744 B
//    -> 1 block/CU, 15 waves (static >64KB proven OK at 69KB; cap 160KiB).
//  - schunk double-buffer removes 1 of 2 barriers/chunk (15 fewer barriers).
// Per-image arithmetic and accumulation order identical to R14 (fp16 x+y lerp,
// fp32 parity-split accum) -> absmax expected exactly 4.882812e-4.
#define NPIX  120
#define NS    120
#define NK    61             // independent bins 0..60; 61..119 mirrored
#define HSTR  123            // H cols: x = 0..122 (pads at 0, 121, 122)
#define HROWS 123            // H rows: y = 0..122 (pads at 0, 121, 122)
#define CHUNK 8              // angles in flight
#define NCHUNK 15            // 120 / 8
#define NT    960            // 8 angle-slots x 120, 15 waves

#if __has_builtin(__builtin_amdgcn_fractf)
#define FRACTF(x) __builtin_amdgcn_fractf(x)
#else
#define FRACTF(x) ((x) - floorf(x))
#endif

__device__ __forceinline__ __half2 lo_h2(uint2 q) { return *reinterpret_cast<__half2*>(&q.x); }
__device__ __forceinline__ __half2 hi_h2(uint2 q) { return *reinterpret_cast<__half2*>(&q.y); }

__global__ void ring_fused(const float* __restrict__ bev,
                           float* __restrict__ out,
                           int B) {
    __shared__ uint2  H[HROWS * HSTR];       // (A,B,C,D) 4xfp16 padded image
    __shared__ float4 schunk[2][CHUNK * NS]; // double-buffered sinogram rows
    __shared__ float4 outAcc[NK];
    __shared__ float  invN[4];               // per-image 1/norm (scalar stores)

    const int tid = threadIdx.x;          // 0..959
    const int b0  = blockIdx.x * 4;       // first image of the quad
    const int al  = tid / NS;             // angle slot 0..7
    const int sk  = tid - al * NS;        // s (radon) / k (Goertzel, if <61)
    if (b0 >= B) return;

    // ---- stage: build H from 4 images (each 8B word owned by 1 thread) -----
    const float* s0 = bev + (size_t)b0 * (NPIX * NPIX);
    const float* s1 = (b0 + 1 < B) ? bev + (size_t)(b0 + 1) * (NPIX * NPIX) : s0;
    const float* s2 = (b0 + 2 < B) ? bev + (size_t)(b0 + 2) * (NPIX * NPIX) : s0;
    const float* s3 = (b0 + 3 < B) ? bev + (size_t)(b0 + 3) * (NPIX * NPIX) : s0;
    for (int i = tid; i < HROWS * HSTR; i += NT) {
        int y = i / HSTR, x = i - y * HSTR;
        float va = 0.f, vb = 0.f, vc = 0.f, vd = 0.f;
        int gx = x - 1, gy = y - 1;
        if (gx >= 0 && gx < NPIX && gy >= 0 && gy < NPIX) {
            int o = gy * NPIX + gx;
            va = s0[o]; vb = s1[o]; vc = s2[o]; vd = s3[o];
        }
        __half2 ab = __floats2half2_rn(va, vb);
        __half2 cd = __floats2half2_rn(vc, vd);
        H[i] = make_uint2(*reinterpret_cast<unsigned*>(&ab),
                          *reinterpret_cast<unsigned*>(&cd));
    }
    __syncthreads();

    // ---- per-thread Goertzel constant (k = sk, used where sk < 61) ---------
    const float coef = 2.f * cosf((float)sk * 0.052359877559829887f);  // 2cos(pi k/60)
    const float sgn  = (sk & 1) ? -1.f : 1.f;
    const double STEP = 6.283185307179586 / 119.0;   // linspace(0,2pi,120) step
    float acc0 = 0.f, acc1 = 0.f, acc2 = 0.f, acc3 = 0.f;

    for (int ch = 0; ch < NCHUNK; ++ch) {
        float4* buf = schunk[ch & 1];
        // ---- radon: sinogram[a = ch*8+al][s = sk] for FOUR images ----------
        {
            int a = ch * CHUNK + al;
            float theta = (float)((double)a * STEP);
            float st = sinf(theta), ct = cosf(theta);
            float sf  = (float)sk - 59.5f;
            float Ax  = fmaf(sf, ct, 60.5f);   // padded px at tv=0
            float Ay  = fmaf(sf, st, 60.5f);   // padded py at tv=0
            float nst = -st;
            float aA0 = 0.f, aA1 = 0.f, aB0 = 0.f, aB1 = 0.f;  // parity chains
            float aC0 = 0.f, aC1 = 0.f, aD0 = 0.f, aD1 = 0.f;
            float tv  = -59.5f;
            #pragma unroll 4
            for (int t = 0; t < NPIX; ++t) {
                float px = fmaf(tv, nst, Ax);
                float py = fmaf(tv, ct,  Ay);
                float cx = fminf(fmaxf(px, 0.f), 121.5f);  // v_med3
                float cy = fminf(fmaxf(py, 0.f), 121.5f);
                int   ix = (int)cx;                        // trunc = floor (cx>=0)
                int   iy = (int)cy;
                float wx = FRACTF(cx);                     // == cx - floor(cx)
                float wy = FRACTF(cy);
                int   ai = __mul24(iy, HSTR) + ix;
                uint2 q00 = H[ai];                         // ds_read2_b64 0/1
                uint2 q01 = H[ai + 1];
                uint2 q10 = H[ai + HSTR];                  // ds_read2_b64 123/124
                uint2 q11 = H[ai + HSTR + 1];
                __half2 wx2 = __float2half2_rn(wx);
                __half2 wy2 = __float2half2_rn(wy);
                __half2 abT = __hfma2(wx2, __hsub2(lo_h2(q01), lo_h2(q00)), lo_h2(q00));
                __half2 abB = __hfma2(wx2, __hsub2(lo_h2(q11), lo_h2(q10)), lo_h2(q10));
                __half2 abV = __hfma2(wy2, __hsub2(abB, abT), abT);
                __half2 cdT = __hfma2(wx2, __hsub2(hi_h2(q01), hi_h2(q00)), hi_h2(q00));
                __half2 cdB = __hfma2(wx2, __hsub2(hi_h2(q11), hi_h2(q10)), hi_h2(q10));
                __half2 cdV = __hfma2(wy2, __hsub2(cdB, cdT), cdT);
                if (t & 1) {
                    aA1 += __low2float(abV); aB1 += __high2float(abV);
                    aC1 += __low2float(cdV); aD1 += __high2float(cdV);
                } else {
                    aA0 += __low2float(abV); aB0 += __high2float(abV);
                    aC0 += __low2float(cdV); aD0 += __high2float(cdV);
                }
                tv += 1.f;
            }
            buf[al * NS + sk] = make_float4(aA0 + aA1, aB0 + aB1,
                                            aC0 + aC1, aD0 + aD1);
        }
        __syncthreads();

        // ---- Goertzel: |F[k = sk]| of row al, 4 images (sk < 61) -----------
        // (no trailing barrier: next chunk writes the OTHER schunk buffer;
        //  reuse of THIS buffer in chunk ch+2 is fenced by ch+1's barrier)
        if (sk < NK) {
            const float4* row = buf + al * NS;
            float u1a = 0.f, u2a = 0.f, u1b = 0.f, u2b = 0.f;
            float u1c = 0.f, u2c = 0.f, u1d = 0.f, u2d = 0.f;
            #pragma unroll 4
            for (int s = 0; s < 60; ++s) {
                float4 lo = row[s];            // broadcast ds_read_b128
                float4 hi = row[s + 60];
                float wa = fmaf(sgn, hi.x, lo.x);
                float wb = fmaf(sgn, hi.y, lo.y);
                float wc = fmaf(sgn, hi.z, lo.z);
                float wd = fmaf(sgn, hi.w, lo.w);
                float va = fmaf(coef, u1a, wa - u2a); u2a = u1a; u1a = va;
                float vb = fmaf(coef, u1b, wb - u2b); u2b = u1b; u1b = vb;
                float vc = fmaf(coef, u1c, wc - u2c); u2c = u1c; u1c = vc;
                float vd = fmaf(coef, u1d, wd - u2d); u2d = u1d; u1d = vd;
            }
            float pa = fmaf(u1a, u1a, fmaf(u2a, u2a, -coef * u1a * u2a));
            float pb = fmaf(u1b, u1b, fmaf(u2b, u2b, -coef * u1b * u2b));
            float pc = fmaf(u1c, u1c, fmaf(u2c, u2c, -coef * u1c * u2c));
            float pd = fmaf(u1d, u1d, fmaf(u2d, u2d, -coef * u1d * u2d));
            pa = fmaxf(pa, 0.f); pb = fmaxf(pb, 0.f);
            pc = fmaxf(pc, 0.f); pd = fmaxf(pd, 0.f);
            acc0 += sqrtf(fmaf(pa, (1.f / 120.f), 1e-15f));  // ortho + EPS_FFT
            acc1 += sqrtf(fmaf(pb, (1.f / 120.f), 1e-15f));
            acc2 += sqrtf(fmaf(pc, (1.f / 120.f), 1e-15f));
            acc3 += sqrtf(fmaf(pd, (1.f / 120.f), 1e-15f));
        }
    }
    __syncthreads();   // all Goertzel reads done before schunk[0] is reused

    // ---- reduce 8 angle-slot partials per bin (deterministic) --------------
    if (sk < NK) schunk[0][al * NS + sk] = make_float4(acc0, acc1, acc2, acc3);
    __syncthreads();
    if (tid < NK) {
        float sa = 0.f, sb = 0.f, sc = 0.f, sd = 0.f;
        for (int a2 = 0; a2 < CHUNK; ++a2) {
            float4 v = schunk[0][a2 * NS + tid];
            sa += v.x; sb += v.y; sc += v.z; sd += v.w;
        }
        outAcc[tid] = make_float4(sa, sb, sc, sd);
    }
    __syncthreads();

    // ---- L2 norm over the full mirrored 120-vector, one thread per image ---
    if (tid < 4) {
        float ssq = 0.f;
        for (int k = 0; k < NK; ++k) {
            float v = ((const float*)&outAcc[k])[tid];
            float wgt = (k == 0 || k == 60) ? 1.f : 2.f;
            ssq = fmaf(wgt * v, v, ssq);
        }
        invN[tid] = 1.f / fmaxf(sqrtf(ssq), 1e-12f);  // per-lane scalar store
    }
    __syncthreads();

    // ---- write fp32 output (Hermitian mirror), 4 images --------------------
    if (tid < 4 * NPIX) {
        int img = tid / NPIX;
        int j   = tid - img * NPIX;
        int k   = (j <= 60) ? j : (NPIX - j);
        int bb  = b0 + img;
        if (bb < B) {
            float v = ((const float*)&outAcc[k])[img] * invN[img];
            out[(size_t)bb * NPIX + j] = v;
        }
    }
}

extern "C" void kernel_launch(void* const* d_in, const int* in_sizes, int n_in,
                              void* d_out, int out_size, void* d_ws, size_t ws_size,
                              hipStream_t stream) {
    const float* bev = (const float*)d_in[0];
    float* out = (float*)d_out;
    int B = in_sizes[0] / (NPIX * NPIX);   // 1024
    int grid = (B + 3) / 4;                // 4 images per block
    hipLaunchKernelGGL(ring_fused, dim3(grid), dim3(NT), 0, stream, bev, out, B);
}